// Round 4
// baseline (482.700 us; speedup 1.0000x reference)
//
#include <hip/hip_runtime.h>
#include <math.h>

#define NN 50000
#define NE 800000
#define INC 32
#define HIDC 64
#define OUTC 8
#define NB_SCAN ((NN + 1023) / 1024)
#define NT_TILES ((NN + 63) / 64)

__device__ __forceinline__ float gelu_exact(float x){
    return 0.5f * x * (1.0f + erff(x * 0.70710678118654752f));
}

__global__ void k_zero_deg(int* deg){
    int i = blockIdx.x*blockDim.x + threadIdx.x;
    for (; i < NN; i += gridDim.x*blockDim.x) deg[i] = 0;
}

// zero the dummy row NN of both h buffers (gather targets for padded edges)
__global__ void k_zero_rows(float* h0, float* h1){
    int i = threadIdx.x;
    if (i < HIDC) h0[(size_t)NN*HIDC + i] = 0.f;
    else          h1[(size_t)NN*HIDC + (i-HIDC)] = 0.f;
}

__global__ void k_hist(const int* __restrict__ dst, int* deg){
    int i = blockIdx.x*blockDim.x + threadIdx.x;
    for (; i < NE; i += gridDim.x*blockDim.x) atomicAdd(&deg[dst[i]], 1);
}

// hierarchical scan: per-chunk local exclusive scan + chunk totals
__global__ __launch_bounds__(1024) void k_scan1(const int* __restrict__ deg,
                                                int* loc, int* bsum){
    __shared__ int sd[1024];
    int b = blockIdx.x, tid = threadIdx.x, g = b*1024 + tid;
    int v = (g < NN) ? deg[g] : 0;
    sd[tid] = v;
    __syncthreads();
    for (int off = 1; off < 1024; off <<= 1){
        int t = (tid >= off) ? sd[tid-off] : 0;
        __syncthreads();
        sd[tid] += t;
        __syncthreads();
    }
    if (g < NN) loc[g] = sd[tid] - v;
    if (tid == 1023) bsum[b] = sd[1023];
}

__global__ void k_scan2(int* bsum){
    int tid = threadIdx.x;
    int orig = (tid < NB_SCAN) ? bsum[tid] : 0;
    int v = orig;
    for (int off = 1; off < 64; off <<= 1){
        int t = __shfl_up(v, off);
        if (tid >= off) v += t;
    }
    if (tid < NB_SCAN) bsum[tid] = v - orig;
}

__global__ void k_scan3(const int* __restrict__ deg, const int* __restrict__ loc,
                        const int* __restrict__ bsum,
                        int* row_ptr, int* fill_pos, float* inv_deg){
    int g = blockIdx.x*blockDim.x + threadIdx.x;
    if (g < NN){
        int e = loc[g] + bsum[g >> 10];
        row_ptr[g] = e; fill_pos[g] = e;
        inv_deg[g] = 1.0f / (float)max(deg[g], 1);
    }
    if (g == 0) row_ptr[NN] = NE;
}

__global__ void k_fill(const int* __restrict__ src, const int* __restrict__ dst,
                       int* fill_pos, int* col){
    int i = blockIdx.x*blockDim.x + threadIdx.x;
    for (; i < NE; i += gridDim.x*blockDim.x){
        int d = dst[i];
        int p = atomicAdd(&fill_pos[d], 1);
        col[p] = src[i];
    }
}

// gather-mean: one wave per node (lane = feature), high occupancy, tiny VGPR
__global__ __launch_bounds__(256) void k_agg(
    const float* __restrict__ h_in,
    const int* __restrict__ row_ptr, const int* __restrict__ col,
    const float* __restrict__ inv_deg,
    float* __restrict__ agg)
{
    int tid = threadIdx.x;
    int wv = tid >> 6, f = tid & 63;
    int g = f >> 4, qoff = (f & 15) * 4;
    for (int node = blockIdx.x*4 + wv; node < NN; node += gridDim.x*4){
        int s0 = row_ptr[node], s1 = row_ptr[node+1];
        float a0 = 0.f, a1 = 0.f, a2 = 0.f, a3 = 0.f;
        for (int p0 = s0; p0 < s1; p0 += 64){
            int cnt = s1 - p0; if (cnt > 64) cnt = 64;
            int cidx = (f < cnt) ? col[p0 + f] : NN;   // NN -> zero row
            int nq = (cnt + 3) >> 2;
            for (int t = 0; t < nq; t++){
                int sidx = __shfl(cidx, t*4 + g);
                float4 v = *(const float4*)&h_in[(size_t)sidx*HIDC + qoff];
                a0 += v.x; a1 += v.y; a2 += v.z; a3 += v.w;
            }
        }
        a0 += __shfl_xor(a0, 16); a0 += __shfl_xor(a0, 32);
        a1 += __shfl_xor(a1, 16); a1 += __shfl_xor(a1, 32);
        a2 += __shfl_xor(a2, 16); a2 += __shfl_xor(a2, 32);
        a3 += __shfl_xor(a3, 16); a3 += __shfl_xor(a3, 32);
        if (g == 0){
            float idg = inv_deg[node];
            float4 o = make_float4(a0*idg, a1*idg, a2*idg, a3*idg);
            *(float4*)&agg[(size_t)node*HIDC + qoff] = o;
        }
    }
}

// SAGE GEMM: lane = node, one wave = 64 nodes. Weights wave-uniform ->
// scalar loads (SGPR operand in v_fmac), inputs per-lane float4 loads.
__global__ __launch_bounds__(256, 4) void k_sage_gemm(
    const float* __restrict__ h_in, const float* __restrict__ agg,
    const float* __restrict__ wl, const float* __restrict__ wr,
    const float* __restrict__ bias, float* __restrict__ h_out)
{
    int tid = threadIdx.x;
    int wv = tid >> 6, lane = tid & 63;
    for (int tile = blockIdx.x*4 + wv; tile < NT_TILES; tile += gridDim.x*4){
        int node = tile*64 + lane;
        int nc = (node < NN) ? node : NN;       // row NN in-bounds (junk ok)
        const float* arow = agg  + (size_t)nc*HIDC;
        const float* hrow = h_in + (size_t)nc*HIDC;
        float out[HIDC];
        #pragma unroll
        for (int f = 0; f < HIDC; f++) out[f] = bias[f];
        #pragma unroll 1
        for (int kc = 0; kc < 4; kc++){
            float4 q0 = *(const float4*)(arow + kc*16 + 0);
            float4 q1 = *(const float4*)(arow + kc*16 + 4);
            float4 q2 = *(const float4*)(arow + kc*16 + 8);
            float4 q3 = *(const float4*)(arow + kc*16 + 12);
            float in16[16] = {q0.x,q0.y,q0.z,q0.w, q1.x,q1.y,q1.z,q1.w,
                              q2.x,q2.y,q2.z,q2.w, q3.x,q3.y,q3.z,q3.w};
            const float* wrow = wl + (size_t)kc*16*HIDC;
            #pragma unroll
            for (int kk = 0; kk < 16; kk++){
                #pragma unroll
                for (int f = 0; f < HIDC; f++)
                    out[f] = fmaf(in16[kk], wrow[kk*HIDC + f], out[f]);
            }
        }
        #pragma unroll 1
        for (int kc = 0; kc < 4; kc++){
            float4 q0 = *(const float4*)(hrow + kc*16 + 0);
            float4 q1 = *(const float4*)(hrow + kc*16 + 4);
            float4 q2 = *(const float4*)(hrow + kc*16 + 8);
            float4 q3 = *(const float4*)(hrow + kc*16 + 12);
            float in16[16] = {q0.x,q0.y,q0.z,q0.w, q1.x,q1.y,q1.z,q1.w,
                              q2.x,q2.y,q2.z,q2.w, q3.x,q3.y,q3.z,q3.w};
            const float* wrow = wr + (size_t)kc*16*HIDC;
            #pragma unroll
            for (int kk = 0; kk < 16; kk++){
                #pragma unroll
                for (int f = 0; f < HIDC; f++)
                    out[f] = fmaf(in16[kk], wrow[kk*HIDC + f], out[f]);
            }
        }
        if (node < NN){
            #pragma unroll
            for (int f4 = 0; f4 < HIDC/4; f4++){
                float4 o = make_float4(gelu_exact(out[f4*4+0]),
                                       gelu_exact(out[f4*4+1]),
                                       gelu_exact(out[f4*4+2]),
                                       gelu_exact(out[f4*4+3]));
                *(float4*)(h_out + (size_t)node*HIDC + f4*4) = o;
            }
        }
    }
}

// encoder: lane = node. stage1 K=32 (loads), stage2 K=64 (register t, fully
// unrolled so t[] stays statically indexed).
__global__ __launch_bounds__(256, 3) void k_encoder(
    const float* __restrict__ x,
    const float* __restrict__ w1, const float* __restrict__ b1,
    const float* __restrict__ w2, const float* __restrict__ b2,
    float* __restrict__ h)
{
    int tid = threadIdx.x;
    int wv = tid >> 6, lane = tid & 63;
    for (int tile = blockIdx.x*4 + wv; tile < NT_TILES; tile += gridDim.x*4){
        int node = tile*64 + lane;
        int nc = (node < NN) ? node : (NN-1);
        const float* xrow = x + (size_t)nc*INC;
        float t[HIDC];
        #pragma unroll
        for (int f = 0; f < HIDC; f++) t[f] = b1[f];
        #pragma unroll 1
        for (int kc = 0; kc < 2; kc++){
            float4 q0 = *(const float4*)(xrow + kc*16 + 0);
            float4 q1 = *(const float4*)(xrow + kc*16 + 4);
            float4 q2 = *(const float4*)(xrow + kc*16 + 8);
            float4 q3 = *(const float4*)(xrow + kc*16 + 12);
            float in16[16] = {q0.x,q0.y,q0.z,q0.w, q1.x,q1.y,q1.z,q1.w,
                              q2.x,q2.y,q2.z,q2.w, q3.x,q3.y,q3.z,q3.w};
            const float* wrow = w1 + (size_t)kc*16*HIDC;
            #pragma unroll
            for (int kk = 0; kk < 16; kk++){
                #pragma unroll
                for (int f = 0; f < HIDC; f++)
                    t[f] = fmaf(in16[kk], wrow[kk*HIDC + f], t[f]);
            }
        }
        #pragma unroll
        for (int f = 0; f < HIDC; f++) t[f] = gelu_exact(t[f]);
        float out[HIDC];
        #pragma unroll
        for (int f = 0; f < HIDC; f++) out[f] = b2[f];
        #pragma unroll
        for (int k = 0; k < HIDC; k++){
            #pragma unroll
            for (int f = 0; f < HIDC; f++)
                out[f] = fmaf(t[k], w2[k*HIDC + f], out[f]);
        }
        if (node < NN){
            #pragma unroll
            for (int f4 = 0; f4 < HIDC/4; f4++){
                float4 o = make_float4(out[f4*4+0], out[f4*4+1],
                                       out[f4*4+2], out[f4*4+3]);
                *(float4*)(h + (size_t)node*HIDC + f4*4) = o;
            }
        }
    }
}

// decoder: lane = node. stage1 K=64 (loads), stage2 K=64 -> 8 outputs.
__global__ __launch_bounds__(256, 3) void k_decoder(
    const float* __restrict__ hbuf,
    const float* __restrict__ w1, const float* __restrict__ b1,
    const float* __restrict__ w2, const float* __restrict__ b2,
    float* __restrict__ out)
{
    int tid = threadIdx.x;
    int wv = tid >> 6, lane = tid & 63;
    for (int tile = blockIdx.x*4 + wv; tile < NT_TILES; tile += gridDim.x*4){
        int node = tile*64 + lane;
        int nc = (node < NN) ? node : NN;      // h buffers have row NN
        const float* hrow = hbuf + (size_t)nc*HIDC;
        float t[HIDC];
        #pragma unroll
        for (int f = 0; f < HIDC; f++) t[f] = b1[f];
        #pragma unroll 1
        for (int kc = 0; kc < 4; kc++){
            float4 q0 = *(const float4*)(hrow + kc*16 + 0);
            float4 q1 = *(const float4*)(hrow + kc*16 + 4);
            float4 q2 = *(const float4*)(hrow + kc*16 + 8);
            float4 q3 = *(const float4*)(hrow + kc*16 + 12);
            float in16[16] = {q0.x,q0.y,q0.z,q0.w, q1.x,q1.y,q1.z,q1.w,
                              q2.x,q2.y,q2.z,q2.w, q3.x,q3.y,q3.z,q3.w};
            const float* wrow = w1 + (size_t)kc*16*HIDC;
            #pragma unroll
            for (int kk = 0; kk < 16; kk++){
                #pragma unroll
                for (int f = 0; f < HIDC; f++)
                    t[f] = fmaf(in16[kk], wrow[kk*HIDC + f], t[f]);
            }
        }
        #pragma unroll
        for (int f = 0; f < HIDC; f++) t[f] = gelu_exact(t[f]);
        float o[OUTC];
        #pragma unroll
        for (int f = 0; f < OUTC; f++) o[f] = b2[f];
        #pragma unroll
        for (int k = 0; k < HIDC; k++){
            #pragma unroll
            for (int f = 0; f < OUTC; f++)
                o[f] = fmaf(t[k], w2[k*OUTC + f], o[f]);
        }
        if (node < NN){
            float4 o0 = make_float4(o[0], o[1], o[2], o[3]);
            float4 o1 = make_float4(o[4], o[5], o[6], o[7]);
            *(float4*)(out + (size_t)node*OUTC + 0) = o0;
            *(float4*)(out + (size_t)node*OUTC + 4) = o1;
        }
    }
}

extern "C" void kernel_launch(void* const* d_in, const int* in_sizes, int n_in,
                              void* d_out, int out_size, void* d_ws, size_t ws_size,
                              hipStream_t stream){
    const float* x      = (const float*)d_in[0];
    const int*   ei     = (const int*)  d_in[1];
    const float* enc_w1 = (const float*)d_in[2];
    const float* enc_b1 = (const float*)d_in[3];
    const float* enc_w2 = (const float*)d_in[4];
    const float* enc_b2 = (const float*)d_in[5];
    const float* sage_wl= (const float*)d_in[6];
    const float* sage_wr= (const float*)d_in[7];
    const float* sage_b = (const float*)d_in[8];
    const float* dec_w1 = (const float*)d_in[9];
    const float* dec_b1 = (const float*)d_in[10];
    const float* dec_w2 = (const float*)d_in[11];
    const float* dec_b2 = (const float*)d_in[12];
    float* out = (float*)d_out;

    char* ws = (char*)d_ws;
    size_t off = 0;
    auto alloc = [&](size_t bytes)->void*{
        void* p = ws + off; off = (off + bytes + 255) & ~(size_t)255; return p;
    };
    int*   deg      = (int*)  alloc((size_t)NN*4);
    int*   loc      = (int*)  alloc((size_t)NN*4);
    int*   bsum     = (int*)  alloc(64*4);
    int*   row_ptr  = (int*)  alloc((size_t)(NN+1)*4);
    int*   fill_pos = (int*)  alloc((size_t)NN*4);
    int*   col      = (int*)  alloc((size_t)NE*4);
    float* inv_deg  = (float*)alloc((size_t)NN*4);
    float* h0       = (float*)alloc((size_t)(NN+1)*HIDC*4);  // +1 zero row
    float* h1       = (float*)alloc((size_t)(NN+1)*HIDC*4);
    float* agg      = (float*)alloc((size_t)(NN+1)*HIDC*4);

    const int* srcv = ei;        // edge_index row 0
    const int* dstv = ei + NE;   // edge_index row 1

    hipLaunchKernelGGL(k_zero_deg, dim3(256),     dim3(256),  0, stream, deg);
    hipLaunchKernelGGL(k_zero_rows,dim3(1),       dim3(128),  0, stream, h0, h1);
    hipLaunchKernelGGL(k_hist,     dim3(1024),    dim3(256),  0, stream, dstv, deg);
    hipLaunchKernelGGL(k_scan1,    dim3(NB_SCAN), dim3(1024), 0, stream, deg, loc, bsum);
    hipLaunchKernelGGL(k_scan2,    dim3(1),       dim3(64),   0, stream, bsum);
    hipLaunchKernelGGL(k_scan3,    dim3((NN+255)/256), dim3(256), 0, stream,
                       deg, loc, bsum, row_ptr, fill_pos, inv_deg);
    hipLaunchKernelGGL(k_fill,     dim3(1024),    dim3(256),  0, stream, srcv, dstv, fill_pos, col);

    int gemm_grid = (NT_TILES + 3) / 4;   // 196 blocks x 4 waves
    hipLaunchKernelGGL(k_encoder,  dim3(gemm_grid), dim3(256), 0, stream,
                       x, enc_w1, enc_b1, enc_w2, enc_b2, h0);

    const float* hin = h0; float* hout = h1;
    for (int l = 0; l < 3; l++){
        hipLaunchKernelGGL(k_agg, dim3(2048), dim3(256), 0, stream,
                           hin, row_ptr, col, inv_deg, agg);
        hipLaunchKernelGGL(k_sage_gemm, dim3(gemm_grid), dim3(256), 0, stream,
                           hin, agg,
                           sage_wl + (size_t)l*HIDC*HIDC,
                           sage_wr + (size_t)l*HIDC*HIDC,
                           sage_b  + (size_t)l*HIDC,
                           hout);
        float* t = (float*)hin; hin = hout; hout = t;
    }

    hipLaunchKernelGGL(k_decoder,  dim3(gemm_grid), dim3(256), 0, stream,
                       hin, dec_w1, dec_b1, dec_w2, dec_b2, out);
}

// Round 5
// 426.933 us; speedup vs baseline: 1.1306x; 1.1306x over previous
//
#include <hip/hip_runtime.h>
#include <math.h>

#define NN 50000
#define NE 800000
#define INC 32
#define HIDC 64
#define OUTC 8
#define NB_SCAN ((NN + 1023) / 1024)
#define NT_TILES ((NN + 63) / 64)      // 782
#define NPAD (NT_TILES * 64)           // 50048 padded rows

__device__ __forceinline__ float gelu_exact(float x){
    return 0.5f * x * (1.0f + erff(x * 0.70710678118654752f));
}

// accumulate out[j] += In[lane][kc*16+kk] * W[kc*16+kk][fbase+j], W stride HIDC
template<int NCH>
__device__ __forceinline__ void gemm_acc(const float* __restrict__ inrow,
                                         const float* __restrict__ W,
                                         int fbase, float out[16]){
    #pragma unroll 2
    for (int kc = 0; kc < NCH; kc++){
        float4 q0 = *(const float4*)(inrow + kc*16 + 0);
        float4 q1 = *(const float4*)(inrow + kc*16 + 4);
        float4 q2 = *(const float4*)(inrow + kc*16 + 8);
        float4 q3 = *(const float4*)(inrow + kc*16 + 12);
        float in16[16] = {q0.x,q0.y,q0.z,q0.w, q1.x,q1.y,q1.z,q1.w,
                          q2.x,q2.y,q2.z,q2.w, q3.x,q3.y,q3.z,q3.w};
        #pragma unroll
        for (int kk = 0; kk < 16; kk++){
            const float* wr = W + (size_t)(kc*16+kk)*HIDC + fbase;
            #pragma unroll
            for (int j = 0; j < 16; j++)
                out[j] = fmaf(in16[kk], wr[j], out[j]);
        }
    }
}

__global__ void k_zero_deg(int* deg){
    int i = blockIdx.x*blockDim.x + threadIdx.x;
    for (; i < NN; i += gridDim.x*blockDim.x) deg[i] = 0;
}

// zero the dummy row NN of both h buffers (gather target for padded edges)
__global__ void k_zero_rows(float* h0, float* h1){
    int i = threadIdx.x;
    if (i < HIDC) h0[(size_t)NN*HIDC + i] = 0.f;
    else          h1[(size_t)NN*HIDC + (i-HIDC)] = 0.f;
}

__global__ void k_hist(const int* __restrict__ dst, int* deg){
    int i = blockIdx.x*blockDim.x + threadIdx.x;
    for (; i < NE; i += gridDim.x*blockDim.x) atomicAdd(&deg[dst[i]], 1);
}

__global__ __launch_bounds__(1024) void k_scan1(const int* __restrict__ deg,
                                                int* loc, int* bsum){
    __shared__ int sd[1024];
    int b = blockIdx.x, tid = threadIdx.x, g = b*1024 + tid;
    int v = (g < NN) ? deg[g] : 0;
    sd[tid] = v;
    __syncthreads();
    for (int off = 1; off < 1024; off <<= 1){
        int t = (tid >= off) ? sd[tid-off] : 0;
        __syncthreads();
        sd[tid] += t;
        __syncthreads();
    }
    if (g < NN) loc[g] = sd[tid] - v;
    if (tid == 1023) bsum[b] = sd[1023];
}

__global__ void k_scan2(int* bsum){
    int tid = threadIdx.x;
    int orig = (tid < NB_SCAN) ? bsum[tid] : 0;
    int v = orig;
    for (int off = 1; off < 64; off <<= 1){
        int t = __shfl_up(v, off);
        if (tid >= off) v += t;
    }
    if (tid < NB_SCAN) bsum[tid] = v - orig;
}

__global__ void k_scan3(const int* __restrict__ deg, const int* __restrict__ loc,
                        const int* __restrict__ bsum,
                        int* row_ptr, int* fill_pos, float* inv_deg){
    int g = blockIdx.x*blockDim.x + threadIdx.x;
    if (g < NN){
        int e = loc[g] + bsum[g >> 10];
        row_ptr[g] = e; fill_pos[g] = e;
        inv_deg[g] = 1.0f / (float)max(deg[g], 1);
    }
    if (g == 0) row_ptr[NN] = NE;
}

__global__ void k_fill(const int* __restrict__ src, const int* __restrict__ dst,
                       int* fill_pos, int* col){
    int i = blockIdx.x*blockDim.x + threadIdx.x;
    for (; i < NE; i += gridDim.x*blockDim.x){
        int d = dst[i];
        int p = atomicAdd(&fill_pos[d], 1);
        col[p] = src[i];
    }
}

// gather-mean: one wave per node (lane = feature)
__global__ __launch_bounds__(256) void k_agg(
    const float* __restrict__ h_in,
    const int* __restrict__ row_ptr, const int* __restrict__ col,
    const float* __restrict__ inv_deg,
    float* __restrict__ agg)
{
    int tid = threadIdx.x;
    int wv = tid >> 6, f = tid & 63;
    int g = f >> 4, qoff = (f & 15) * 4;
    for (int node = blockIdx.x*4 + wv; node < NN; node += gridDim.x*4){
        int s0 = row_ptr[node], s1 = row_ptr[node+1];
        float a0 = 0.f, a1 = 0.f, a2 = 0.f, a3 = 0.f;
        for (int p0 = s0; p0 < s1; p0 += 64){
            int cnt = s1 - p0; if (cnt > 64) cnt = 64;
            int cidx = (f < cnt) ? col[p0 + f] : NN;   // NN -> zero row
            int nq = (cnt + 3) >> 2;
            for (int t = 0; t < nq; t++){
                int sidx = __shfl(cidx, t*4 + g);
                float4 v = *(const float4*)&h_in[(size_t)sidx*HIDC + qoff];
                a0 += v.x; a1 += v.y; a2 += v.z; a3 += v.w;
            }
        }
        a0 += __shfl_xor(a0, 16); a0 += __shfl_xor(a0, 32);
        a1 += __shfl_xor(a1, 16); a1 += __shfl_xor(a1, 32);
        a2 += __shfl_xor(a2, 16); a2 += __shfl_xor(a2, 32);
        a3 += __shfl_xor(a3, 16); a3 += __shfl_xor(a3, 32);
        if (g == 0){
            float idg = inv_deg[node];
            float4 o = make_float4(a0*idg, a1*idg, a2*idg, a3*idg);
            *(float4*)&agg[(size_t)node*HIDC + qoff] = o;
        }
    }
}

// ---- lane=node GEMM kernels: 1 wave/block, grid = tiles*4, blockIdx
// encodes (tile, fchunk) so fbase is scalar -> weights via s_load ----

// enc stage 1: tbuf = gelu(x @ w1 + b1)
__global__ __launch_bounds__(64) void k_enc1(
    const float* __restrict__ x, const float* __restrict__ w1,
    const float* __restrict__ b1, float* __restrict__ tbuf)
{
    int id = blockIdx.x, tile = id >> 2, fb = (id & 3) * 16;
    int lane = threadIdx.x;
    int node = tile*64 + lane;
    int nc = (node < NN) ? node : (NN-1);     // x has exactly NN rows
    float out[16];
    #pragma unroll
    for (int j = 0; j < 16; j++) out[j] = b1[fb + j];
    gemm_acc<2>(x + (size_t)nc*INC, w1, fb, out);
    float* dst = tbuf + (size_t)node*HIDC + fb;
    #pragma unroll
    for (int j4 = 0; j4 < 4; j4++){
        float4 o = make_float4(gelu_exact(out[j4*4+0]), gelu_exact(out[j4*4+1]),
                               gelu_exact(out[j4*4+2]), gelu_exact(out[j4*4+3]));
        *(float4*)(dst + j4*4) = o;           // tbuf padded: unmasked
    }
}

// enc stage 2: h = tbuf @ w2 + b2  (no gelu)
__global__ __launch_bounds__(64) void k_enc2(
    const float* __restrict__ tbuf, const float* __restrict__ w2,
    const float* __restrict__ b2, float* __restrict__ h)
{
    int id = blockIdx.x, tile = id >> 2, fb = (id & 3) * 16;
    int lane = threadIdx.x;
    int node = tile*64 + lane;
    float out[16];
    #pragma unroll
    for (int j = 0; j < 16; j++) out[j] = b2[fb + j];
    gemm_acc<4>(tbuf + (size_t)node*HIDC, w2, fb, out);
    if (node < NN){                            // keep zero row intact
        float* dst = h + (size_t)node*HIDC + fb;
        #pragma unroll
        for (int j4 = 0; j4 < 4; j4++)
            *(float4*)(dst + j4*4) = make_float4(out[j4*4+0], out[j4*4+1],
                                                 out[j4*4+2], out[j4*4+3]);
    }
}

// sage GEMM: h_out = gelu(agg @ wl + h_in @ wr + b)
__global__ __launch_bounds__(64) void k_sage16(
    const float* __restrict__ h_in, const float* __restrict__ agg,
    const float* __restrict__ wl, const float* __restrict__ wr,
    const float* __restrict__ bias, float* __restrict__ h_out)
{
    int id = blockIdx.x, tile = id >> 2, fb = (id & 3) * 16;
    int lane = threadIdx.x;
    int node = tile*64 + lane;
    float out[16];
    #pragma unroll
    for (int j = 0; j < 16; j++) out[j] = bias[fb + j];
    gemm_acc<4>(agg  + (size_t)node*HIDC, wl, fb, out);
    gemm_acc<4>(h_in + (size_t)node*HIDC, wr, fb, out);
    if (node < NN){
        float* dst = h_out + (size_t)node*HIDC + fb;
        #pragma unroll
        for (int j4 = 0; j4 < 4; j4++){
            float4 o = make_float4(gelu_exact(out[j4*4+0]), gelu_exact(out[j4*4+1]),
                                   gelu_exact(out[j4*4+2]), gelu_exact(out[j4*4+3]));
            *(float4*)(dst + j4*4) = o;
        }
    }
}

// dec stage 1: tbuf = gelu(h @ w1 + b1)
__global__ __launch_bounds__(64) void k_dec1(
    const float* __restrict__ h, const float* __restrict__ w1,
    const float* __restrict__ b1, float* __restrict__ tbuf)
{
    int id = blockIdx.x, tile = id >> 2, fb = (id & 3) * 16;
    int lane = threadIdx.x;
    int node = tile*64 + lane;
    float out[16];
    #pragma unroll
    for (int j = 0; j < 16; j++) out[j] = b1[fb + j];
    gemm_acc<4>(h + (size_t)node*HIDC, w1, fb, out);
    float* dst = tbuf + (size_t)node*HIDC + fb;
    #pragma unroll
    for (int j4 = 0; j4 < 4; j4++){
        float4 o = make_float4(gelu_exact(out[j4*4+0]), gelu_exact(out[j4*4+1]),
                               gelu_exact(out[j4*4+2]), gelu_exact(out[j4*4+3]));
        *(float4*)(dst + j4*4) = o;
    }
}

// dec stage 2: out = tbuf @ w2 + b2 (8 outputs), one wave per tile
__global__ __launch_bounds__(64) void k_dec2(
    const float* __restrict__ tbuf, const float* __restrict__ w2,
    const float* __restrict__ b2, float* __restrict__ out)
{
    int tile = blockIdx.x;
    int lane = threadIdx.x;
    int node = tile*64 + lane;
    const float* inrow = tbuf + (size_t)node*HIDC;
    float o[OUTC];
    #pragma unroll
    for (int j = 0; j < OUTC; j++) o[j] = b2[j];
    #pragma unroll 2
    for (int kc = 0; kc < 4; kc++){
        float4 q0 = *(const float4*)(inrow + kc*16 + 0);
        float4 q1 = *(const float4*)(inrow + kc*16 + 4);
        float4 q2 = *(const float4*)(inrow + kc*16 + 8);
        float4 q3 = *(const float4*)(inrow + kc*16 + 12);
        float in16[16] = {q0.x,q0.y,q0.z,q0.w, q1.x,q1.y,q1.z,q1.w,
                          q2.x,q2.y,q2.z,q2.w, q3.x,q3.y,q3.z,q3.w};
        #pragma unroll
        for (int kk = 0; kk < 16; kk++){
            const float* wr = w2 + (size_t)(kc*16+kk)*OUTC;
            #pragma unroll
            for (int j = 0; j < OUTC; j++)
                o[j] = fmaf(in16[kk], wr[j], o[j]);
        }
    }
    if (node < NN){
        *(float4*)(out + (size_t)node*OUTC + 0) = make_float4(o[0],o[1],o[2],o[3]);
        *(float4*)(out + (size_t)node*OUTC + 4) = make_float4(o[4],o[5],o[6],o[7]);
    }
}

extern "C" void kernel_launch(void* const* d_in, const int* in_sizes, int n_in,
                              void* d_out, int out_size, void* d_ws, size_t ws_size,
                              hipStream_t stream){
    const float* x      = (const float*)d_in[0];
    const int*   ei     = (const int*)  d_in[1];
    const float* enc_w1 = (const float*)d_in[2];
    const float* enc_b1 = (const float*)d_in[3];
    const float* enc_w2 = (const float*)d_in[4];
    const float* enc_b2 = (const float*)d_in[5];
    const float* sage_wl= (const float*)d_in[6];
    const float* sage_wr= (const float*)d_in[7];
    const float* sage_b = (const float*)d_in[8];
    const float* dec_w1 = (const float*)d_in[9];
    const float* dec_b1 = (const float*)d_in[10];
    const float* dec_w2 = (const float*)d_in[11];
    const float* dec_b2 = (const float*)d_in[12];
    float* out = (float*)d_out;

    char* ws = (char*)d_ws;
    size_t off = 0;
    auto alloc = [&](size_t bytes)->void*{
        void* p = ws + off; off = (off + bytes + 255) & ~(size_t)255; return p;
    };
    int*   deg      = (int*)  alloc((size_t)NN*4);
    int*   loc      = (int*)  alloc((size_t)NN*4);
    int*   bsum     = (int*)  alloc(64*4);
    int*   row_ptr  = (int*)  alloc((size_t)(NN+1)*4);
    int*   fill_pos = (int*)  alloc((size_t)NN*4);
    int*   col      = (int*)  alloc((size_t)NE*4);
    float* inv_deg  = (float*)alloc((size_t)NN*4);
    float* h0       = (float*)alloc((size_t)NPAD*HIDC*4);
    float* h1       = (float*)alloc((size_t)NPAD*HIDC*4);
    float* agg      = (float*)alloc((size_t)NPAD*HIDC*4);  // doubles as tbuf

    const int* srcv = ei;        // edge_index row 0
    const int* dstv = ei + NE;   // edge_index row 1

    hipLaunchKernelGGL(k_zero_deg, dim3(256),     dim3(256),  0, stream, deg);
    hipLaunchKernelGGL(k_zero_rows,dim3(1),       dim3(128),  0, stream, h0, h1);
    hipLaunchKernelGGL(k_hist,     dim3(1024),    dim3(256),  0, stream, dstv, deg);
    hipLaunchKernelGGL(k_scan1,    dim3(NB_SCAN), dim3(1024), 0, stream, deg, loc, bsum);
    hipLaunchKernelGGL(k_scan2,    dim3(1),       dim3(64),   0, stream, bsum);
    hipLaunchKernelGGL(k_scan3,    dim3((NN+255)/256), dim3(256), 0, stream,
                       deg, loc, bsum, row_ptr, fill_pos, inv_deg);
    hipLaunchKernelGGL(k_fill,     dim3(1024),    dim3(256),  0, stream, srcv, dstv, fill_pos, col);

    int g16 = NT_TILES * 4;      // 3128 one-wave blocks
    hipLaunchKernelGGL(k_enc1, dim3(g16), dim3(64), 0, stream, x, enc_w1, enc_b1, agg);
    hipLaunchKernelGGL(k_enc2, dim3(g16), dim3(64), 0, stream, agg, enc_w2, enc_b2, h0);

    const float* hin = h0; float* hout = h1;
    for (int l = 0; l < 3; l++){
        hipLaunchKernelGGL(k_agg, dim3(2048), dim3(256), 0, stream,
                           hin, row_ptr, col, inv_deg, agg);
        hipLaunchKernelGGL(k_sage16, dim3(g16), dim3(64), 0, stream,
                           hin, agg,
                           sage_wl + (size_t)l*HIDC*HIDC,
                           sage_wr + (size_t)l*HIDC*HIDC,
                           sage_b  + (size_t)l*HIDC,
                           hout);
        float* t = (float*)hin; hin = hout; hout = t;
    }

    hipLaunchKernelGGL(k_dec1, dim3(g16),      dim3(64), 0, stream,
                       hin, dec_w1, dec_b1, agg);
    hipLaunchKernelGGL(k_dec2, dim3(NT_TILES), dim3(64), 0, stream,
                       agg, dec_w2, dec_b2, out);
}